// Round 1
// baseline (666.266 us; speedup 1.0000x reference)
//
#include <hip/hip_runtime.h>

#define HH 384
#define WW 384
#define BB 8
#define CC 3
#define NMASK (BB*CC)        // 24
#define PLANE (HH*WW)        // 147456
#define NPLANES (NMASK*2)    // 48
#define INF_F 1.0e6f

// ---------------------------------------------------------------------------
// ws layout:
//   float planes[NPLANES][PLANE]   plane p = mask*2 + dir (dir 0 = fg set ~mask, 1 = bg set mask)
//   unsigned maxv[NPLANES]         float bits of per-plane max dist (>=0 so uint order == float order)
//   int flags[NMASK]               any(mask) per (b,c)
//   float acc[1]                   global loss accumulator
// ---------------------------------------------------------------------------

__global__ void initk(unsigned* __restrict__ maxv, int* __restrict__ flags,
                      float* __restrict__ acc) {
    int t = threadIdx.x;
    if (t < NPLANES) maxv[t] = 0u;
    if (t < NMASK)   flags[t] = 0;
    if (t == 0)      acc[0] = 0.0f;
}

// One thread per (mask, column). fwd scan down, bwd scan up, g = min.
// Replicates reference fp32 arithmetic: d = row ? 0 : carry + 1, carry0 = 1e6.
__global__ void colscan(const int* __restrict__ targets,
                        float* __restrict__ planes,
                        int* __restrict__ flags) {
    int gid = blockIdx.x * blockDim.x + threadIdx.x;
    if (gid >= NMASK * WW) return;
    int m = gid / WW;
    int j = gid - m * WW;
    int b = m / CC;
    int c = m - b * CC;
    const int* tg = targets + b * PLANE + j;
    float* gfg = planes + (m * 2 + 0) * PLANE + j;   // set = (t != c)
    float* gbg = planes + (m * 2 + 1) * PLANE + j;   // set = (t == c)

    unsigned long long bits[6] = {0, 0, 0, 0, 0, 0}; // mask bits per row
    float cf = INF_F, cb = INF_F;
    bool anyb = false;
    for (int i = 0; i < HH; ++i) {
        int t = tg[i * WW];
        bool is = (t == c);
        if (is) { bits[i >> 6] |= (1ull << (i & 63)); anyb = true; }
        cf = (!is) ? 0.0f : (cf + 1.0f);
        cb = is    ? 0.0f : (cb + 1.0f);
        gfg[i * WW] = cf;
        gbg[i * WW] = cb;
    }
    cf = INF_F; cb = INF_F;
    for (int i = HH - 1; i >= 0; --i) {
        bool is = (bits[i >> 6] >> (i & 63)) & 1ull;
        cf = (!is) ? 0.0f : (cf + 1.0f);
        cb = is    ? 0.0f : (cb + 1.0f);
        gfg[i * WW] = fminf(gfg[i * WW], cf);
        gbg[i * WW] = fminf(gbg[i * WW], cb);
    }
    if (anyb) atomicOr(&flags[m], 1);
}

// One block per (plane, row): exact 1D lower-envelope via brute-force min.
// d2[j] = min_k (j-k)^2 + g2[k]; dist = sqrt(d2). In-place over the g plane.
// Also reduces the row max and atomicMax's into maxv[plane].
__global__ __launch_bounds__(WW) void edt_rows(float* __restrict__ planes,
                                               unsigned* __restrict__ maxv) {
    __shared__ float g2[WW];
    __shared__ float wmax[8];
    int i = blockIdx.x;   // row
    int p = blockIdx.y;   // plane
    int j = threadIdx.x;
    float* base = planes + (size_t)p * PLANE + i * WW;
    float g = base[j];
    g2[j] = g * g;
    __syncthreads();

    float mn = 3.4e38f;
    float diff = (float)j;       // (j - k), exact integer-valued fp32
#pragma unroll 8
    for (int k = 0; k < WW; ++k) {
        float cand = fmaf(diff, diff, g2[k]);  // diff^2 exact => same rounding as ref
        mn = fminf(mn, cand);
        diff -= 1.0f;
    }
    float d = sqrtf(mn);
    base[j] = d;

    // block max -> atomicMax (floats >= 0 so uint bit order works)
    float v = d;
    for (int off = 32; off > 0; off >>= 1) v = fmaxf(v, __shfl_down(v, off));
    int lane = j & 63, wid = j >> 6;
    if (lane == 0) wmax[wid] = v;
    __syncthreads();
    if (j == 0) {
        float mx = wmax[0];
        for (int w = 1; w < WW / 64; ++w) mx = fmaxf(mx, wmax[w]);
        atomicMax(maxv + p, __float_as_uint(mx));
    }
}

// Fused: softmax over C, sdf = bg/max_bg - fg/max_fg (0 if mask empty),
// accumulate probs*sdf, block-reduce, atomicAdd.
__global__ __launch_bounds__(256) void reduce_loss(const float* __restrict__ logits,
                                                   const float* __restrict__ planes,
                                                   const unsigned* __restrict__ maxv,
                                                   const int* __restrict__ flags,
                                                   float* __restrict__ acc) {
    __shared__ float wsum[4];
    int gid = blockIdx.x * blockDim.x + threadIdx.x;  // < BB*PLANE
    int b = gid / PLANE;
    int pix = gid - b * PLANE;

    const float* lg = logits + (size_t)b * CC * PLANE + pix;
    float l0 = lg[0], l1 = lg[PLANE], l2 = lg[2 * PLANE];
    float mx = fmaxf(l0, fmaxf(l1, l2));
    float e0 = __expf(0.0f); // placeholder removed below
    (void)e0;
    float x0 = expf(l0 - mx), x1 = expf(l1 - mx), x2 = expf(l2 - mx);
    float s = x0 + x1 + x2;
    float pr[3] = {x0 / s, x1 / s, x2 / s};

    float local = 0.0f;
    for (int c = 0; c < CC; ++c) {
        int m = b * CC + c;
        float sdf = 0.0f;
        if (flags[m]) {
            float fg = planes[(size_t)(m * 2 + 0) * PLANE + pix];
            float bg = planes[(size_t)(m * 2 + 1) * PLANE + pix];
            float mfg = fmaxf(__uint_as_float(maxv[m * 2 + 0]), 1e-12f);
            float mbg = fmaxf(__uint_as_float(maxv[m * 2 + 1]), 1e-12f);
            sdf = bg / mbg - fg / mfg;
        }
        local += pr[c] * sdf;
    }

    // block reduction: wave shuffle then LDS across 4 waves
    for (int off = 32; off > 0; off >>= 1) local += __shfl_down(local, off);
    int lane = threadIdx.x & 63, wid = threadIdx.x >> 6;
    if (lane == 0) wsum[wid] = local;
    __syncthreads();
    if (threadIdx.x == 0) {
        float bs = wsum[0] + wsum[1] + wsum[2] + wsum[3];
        atomicAdd(acc, bs);
    }
}

__global__ void finalize(const float* __restrict__ acc, float* __restrict__ out) {
    out[0] = acc[0] / (float)((size_t)BB * CC * PLANE);
}

extern "C" void kernel_launch(void* const* d_in, const int* in_sizes, int n_in,
                              void* d_out, int out_size, void* d_ws, size_t ws_size,
                              hipStream_t stream) {
    const float* logits = (const float*)d_in[0];   // [8,3,384,384] f32
    const int* targets = (const int*)d_in[1];      // [8,384,384] i32
    float* out = (float*)d_out;                    // scalar f32

    float* planes = (float*)d_ws;                              // 48 * PLANE floats
    unsigned* maxv = (unsigned*)(planes + (size_t)NPLANES * PLANE);
    int* flags = (int*)(maxv + NPLANES);
    float* acc = (float*)(flags + NMASK);

    initk<<<1, 128, 0, stream>>>(maxv, flags, acc);

    {
        int total = NMASK * WW;                    // 9216
        int blk = 256;
        colscan<<<(total + blk - 1) / blk, blk, 0, stream>>>(targets, planes, flags);
    }

    {
        dim3 grid(HH, NPLANES);                    // 384 x 48
        edt_rows<<<grid, WW, 0, stream>>>(planes, maxv);
    }

    {
        int total = BB * PLANE;                    // 1179648
        int blk = 256;
        reduce_loss<<<total / blk, blk, 0, stream>>>(logits, planes, maxv, flags, acc);
    }

    finalize<<<1, 1, 0, stream>>>(acc, out);
}

// Round 2
// 288.359 us; speedup vs baseline: 2.3105x; 2.3105x over previous
//
#include <hip/hip_runtime.h>

typedef unsigned long long u64;

#define HH 384
#define WW 384
#define BB 8
#define CC 3
#define NMASK (BB*CC)        // 24
#define PLANE (HH*WW)        // 147456
#define NPLANES (NMASK*2)    // 48
#define NW 6                 // 384 rows = 6 x 64-bit words exactly
#define INF_F 1.0e6f

// ---------------------------------------------------------------------------
// ws layout:
//   float planes[NPLANES][PLANE]      plane p = (b*CC+c)*2 + d  (d0=fg set ~mask, d1=bg set mask)
//   u64   bm[BB][CC][NW][WW]          column seed bitmask, bit r of word w = (targets[b][64w+r][j]==c)
//   unsigned maxv[NPLANES]            float bits of per-plane max dist (>=0 so uint order == float order)
//   int flags[NMASK]                  any(mask) per (b,c)
//   float acc[1]                      global loss accumulator
// ---------------------------------------------------------------------------

__global__ void initk(unsigned* __restrict__ maxv, int* __restrict__ flags,
                      float* __restrict__ acc) {
    int t = threadIdx.x;
    if (t < NPLANES) maxv[t] = 0u;
    if (t < NMASK)   flags[t] = 0;
    if (t == 0)      acc[0] = 0.0f;
}

// One block per (b, w): 384 threads, thread j builds the 64-row bitmask word for
// its column for all 3 classes. Loads coalesced across j; 64 independent loads
// per thread pipeline fully. Also sets flags[b*CC+c] (any seed).
__global__ __launch_bounds__(WW) void buildbm(const int* __restrict__ targets,
                                              u64* __restrict__ bm,
                                              int* __restrict__ flags) {
    int b = blockIdx.x / NW;
    int w = blockIdx.x - b * NW;
    int j = threadIdx.x;
    const int* tg = targets + (size_t)b * PLANE + (w * 64) * WW + j;
    u64 m0 = 0, m1 = 0, m2 = 0;
#pragma unroll 8
    for (int r = 0; r < 64; ++r) {
        int t = tg[r * WW];
        u64 bit = 1ull << r;
        if (t == 0) m0 |= bit;
        else if (t == 1) m1 |= bit;
        else m2 |= bit;
    }
    bm[(((size_t)b * CC + 0) * NW + w) * WW + j] = m0;
    bm[(((size_t)b * CC + 1) * NW + w) * WW + j] = m1;
    bm[(((size_t)b * CC + 2) * NW + w) * WW + j] = m2;
    bool lane0 = (threadIdx.x & 63) == 0;
    if (__any(m0 != 0) && lane0) atomicOr(&flags[b * CC + 0], 1);
    if (__any(m1 != 0) && lane0) atomicOr(&flags[b * CC + 1], 1);
    if (__any(m2 != 0) && lane0) atomicOr(&flags[b * CC + 2], 1);
}

// One block per (b, row i): 384 threads. Thread j reconstructs the exact
// column distance g (reference fp32 values: integer dist, or 1e6+k if no seed)
// for all 6 planes from the bitmasks, squares into LDS, then row-EDT with an
// expanding-ring search (safe prune: r*r >= mn implies candidate >= mn).
__global__ __launch_bounds__(WW) void edt_fused(const u64* __restrict__ bm,
                                                float* __restrict__ planes,
                                                unsigned* __restrict__ maxv) {
    __shared__ float g2s[6][WW];
    __shared__ float wmax[6][WW / 64];
    int i = blockIdx.x;
    int b = blockIdx.y;
    int j = threadIdx.x;
    int wi = i >> 6, bi = i & 63;
    u64 lowmask = (bi == 63) ? ~0ull : ((1ull << (bi + 1)) - 1ull); // bits 0..bi
    u64 himask = ~(lowmask >> 1);                                   // bits bi..63

#pragma unroll
    for (int c = 0; c < CC; ++c) {
        u64 wb[NW];
#pragma unroll
        for (int w = 0; w < NW; ++w)
            wb[w] = bm[(((size_t)b * CC + c) * NW + w) * WW + j];
#pragma unroll
        for (int d = 0; d < 2; ++d) {
            // d=0: fg set = (t != c) = complement; d=1: bg set = (t == c)
            int last = -1, next = -1;
#pragma unroll
            for (int w = 0; w < NW; ++w) {
                u64 raw = (d == 0) ? ~wb[w] : wb[w];
                u64 mlo = (w < wi) ? raw : ((w == wi) ? (raw & lowmask) : 0ull);
                if (mlo) last = (w << 6) + 63 - __builtin_clzll(mlo | 1ull);
            }
#pragma unroll
            for (int w = NW - 1; w >= 0; --w) {
                u64 raw = (d == 0) ? ~wb[w] : wb[w];
                u64 mhi = (w > wi) ? raw : ((w == wi) ? (raw & himask) : 0ull);
                if (mhi) next = (w << 6) + (int)__builtin_ctzll(mhi | 0x8000000000000000ull);
            }
            float fwd = (last >= 0) ? (float)(i - last) : (INF_F + (float)(i + 1));
            float bwd = (next >= 0) ? (float)(next - i) : (INF_F + (float)(HH - i));
            float g = fminf(fwd, bwd);
            g2s[c * 2 + d][j] = g * g;
        }
    }
    __syncthreads();

    float dloc[6];
#pragma unroll
    for (int p6 = 0; p6 < 6; ++p6) {
        const float* g2 = g2s[p6];
        float mn = g2[j];
        for (int r = 1; r < WW; ++r) {
            float rr = (float)(r * r);          // exact fp32 integer
            if (rr >= mn) break;                // all further candidates >= rr >= mn
            int kl = j - r, kr = j + r;
            if (kl >= 0) mn = fminf(mn, rr + g2[kl]);
            if (kr < WW) mn = fminf(mn, rr + g2[kr]);
        }
        dloc[p6] = sqrtf(mn);
    }

    // store + per-plane block max
    size_t rowoff = (size_t)i * WW + j;
    int lane = j & 63, wid = j >> 6;
#pragma unroll
    for (int p6 = 0; p6 < 6; ++p6) {
        planes[((size_t)(b * 6 + p6)) * PLANE + rowoff] = dloc[p6];
        float v = dloc[p6];
        for (int off = 32; off > 0; off >>= 1) v = fmaxf(v, __shfl_down(v, off));
        if (lane == 0) wmax[p6][wid] = v;
    }
    __syncthreads();
    if (j < 6) {
        float mx = wmax[j][0];
#pragma unroll
        for (int w = 1; w < WW / 64; ++w) mx = fmaxf(mx, wmax[j][w]);
        atomicMax(maxv + b * 6 + j, __float_as_uint(mx));
    }
}

// Fused: softmax over C, sdf = bg/max_bg - fg/max_fg (0 if mask empty),
// accumulate probs*sdf, block-reduce, atomicAdd.
__global__ __launch_bounds__(256) void reduce_loss(const float* __restrict__ logits,
                                                   const float* __restrict__ planes,
                                                   const unsigned* __restrict__ maxv,
                                                   const int* __restrict__ flags,
                                                   float* __restrict__ acc) {
    __shared__ float wsum[4];
    int gid = blockIdx.x * blockDim.x + threadIdx.x;  // < BB*PLANE
    int b = gid / PLANE;
    int pix = gid - b * PLANE;

    const float* lg = logits + (size_t)b * CC * PLANE + pix;
    float l0 = lg[0], l1 = lg[PLANE], l2 = lg[2 * PLANE];
    float mx = fmaxf(l0, fmaxf(l1, l2));
    float x0 = expf(l0 - mx), x1 = expf(l1 - mx), x2 = expf(l2 - mx);
    float s = x0 + x1 + x2;
    float pr[3] = {x0 / s, x1 / s, x2 / s};

    float local = 0.0f;
#pragma unroll
    for (int c = 0; c < CC; ++c) {
        int m = b * CC + c;
        float sdf = 0.0f;
        if (flags[m]) {
            float fg = planes[(size_t)(m * 2 + 0) * PLANE + pix];
            float bg = planes[(size_t)(m * 2 + 1) * PLANE + pix];
            float mfg = fmaxf(__uint_as_float(maxv[m * 2 + 0]), 1e-12f);
            float mbg = fmaxf(__uint_as_float(maxv[m * 2 + 1]), 1e-12f);
            sdf = bg / mbg - fg / mfg;
        }
        local += pr[c] * sdf;
    }

    for (int off = 32; off > 0; off >>= 1) local += __shfl_down(local, off);
    int lane = threadIdx.x & 63, wid = threadIdx.x >> 6;
    if (lane == 0) wsum[wid] = local;
    __syncthreads();
    if (threadIdx.x == 0) {
        float bs = wsum[0] + wsum[1] + wsum[2] + wsum[3];
        atomicAdd(acc, bs);
    }
}

__global__ void finalize(const float* __restrict__ acc, float* __restrict__ out) {
    out[0] = acc[0] / (float)((size_t)BB * CC * PLANE);
}

extern "C" void kernel_launch(void* const* d_in, const int* in_sizes, int n_in,
                              void* d_out, int out_size, void* d_ws, size_t ws_size,
                              hipStream_t stream) {
    const float* logits = (const float*)d_in[0];   // [8,3,384,384] f32
    const int* targets = (const int*)d_in[1];      // [8,384,384] i32
    float* out = (float*)d_out;                    // scalar f32

    float* planes = (float*)d_ws;                               // 48 * PLANE floats
    u64* bm = (u64*)(planes + (size_t)NPLANES * PLANE);         // 8*3*6*384 u64
    unsigned* maxv = (unsigned*)(bm + (size_t)BB * CC * NW * WW);
    int* flags = (int*)(maxv + NPLANES);
    float* acc = (float*)(flags + NMASK);

    initk<<<1, 128, 0, stream>>>(maxv, flags, acc);

    buildbm<<<BB * NW, WW, 0, stream>>>(targets, bm, flags);    // 48 blocks

    {
        dim3 grid(HH, BB);                                      // 384 x 8 = 3072 blocks
        edt_fused<<<grid, WW, 0, stream>>>(bm, planes, maxv);
    }

    {
        int total = BB * PLANE;                                 // 1179648
        reduce_loss<<<total / 256, 256, 0, stream>>>(logits, planes, maxv, flags, acc);
    }

    finalize<<<1, 1, 0, stream>>>(acc, out);
}

// Round 3
// 159.941 us; speedup vs baseline: 4.1657x; 1.8029x over previous
//
#include <hip/hip_runtime.h>

typedef unsigned long long u64;

#define HH 384
#define WW 384
#define BB 8
#define CC 3
#define NMASK (BB*CC)        // 24
#define PLANE (HH*WW)        // 147456
#define NPLANES (NMASK*2)    // 48
#define NW 6                 // 384 rows = 6 x 64-bit words exactly
#define INF_F 1.0e6f
#define RL_BLOCKS 1152
#define RL_THREADS 256

// ---------------------------------------------------------------------------
// ws layout:
//   float planes[NPLANES][PLANE]      plane p = (b*CC+c)*2 + d  (d0=fg set ~mask, d1=bg set mask)
//   u64   bm[BB][CC][NW][WW]          column seed bitmask
//   float rowmax[NPLANES][HH]         per-(plane,row) max dist
//   float maxv[NPLANES]               per-plane max dist
//   int   flags[NMASK]                any(mask) per (b,c)
//   float partials[RL_BLOCKS]         per-block loss partial sums
// ---------------------------------------------------------------------------

__global__ void initk(int* __restrict__ flags) {
    int t = threadIdx.x;
    if (t < NMASK) flags[t] = 0;
}

// One block per (b, w): 384 threads, thread j builds the 64-row bitmask word
// for its column for all 3 classes. Also sets flags[b*CC+c] (any seed).
__global__ __launch_bounds__(WW) void buildbm(const int* __restrict__ targets,
                                              u64* __restrict__ bm,
                                              int* __restrict__ flags) {
    int b = blockIdx.x / NW;
    int w = blockIdx.x - b * NW;
    int j = threadIdx.x;
    const int* tg = targets + (size_t)b * PLANE + (w * 64) * WW + j;
    u64 m0 = 0, m1 = 0, m2 = 0;
#pragma unroll 8
    for (int r = 0; r < 64; ++r) {
        int t = tg[r * WW];
        u64 bit = 1ull << r;
        if (t == 0) m0 |= bit;
        else if (t == 1) m1 |= bit;
        else m2 |= bit;
    }
    bm[(((size_t)b * CC + 0) * NW + w) * WW + j] = m0;
    bm[(((size_t)b * CC + 1) * NW + w) * WW + j] = m1;
    bm[(((size_t)b * CC + 2) * NW + w) * WW + j] = m2;
    bool lane0 = (threadIdx.x & 63) == 0;
    if (__any(m0 != 0) && lane0) atomicOr(&flags[b * CC + 0], 1);
    if (__any(m1 != 0) && lane0) atomicOr(&flags[b * CC + 1], 1);
    if (__any(m2 != 0) && lane0) atomicOr(&flags[b * CC + 2], 1);
}

// One block per (b, row i): thread j reconstructs the exact column distance g
// for all 6 planes from the bitmasks, squares into LDS, then row-EDT with an
// expanding-ring search (safe prune: r*r >= mn implies candidate >= mn).
// Row max written as plain store to rowmax (no atomics).
__global__ __launch_bounds__(WW) void edt_fused(const u64* __restrict__ bm,
                                                float* __restrict__ planes,
                                                float* __restrict__ rowmax) {
    __shared__ float g2s[6][WW];
    __shared__ float wmax[6][WW / 64];
    int i = blockIdx.x;
    int b = blockIdx.y;
    int j = threadIdx.x;
    int wi = i >> 6, bi = i & 63;
    u64 lowmask = (bi == 63) ? ~0ull : ((1ull << (bi + 1)) - 1ull); // bits 0..bi
    u64 himask = ~(lowmask >> 1);                                   // bits bi..63

#pragma unroll
    for (int c = 0; c < CC; ++c) {
        u64 wb[NW];
#pragma unroll
        for (int w = 0; w < NW; ++w)
            wb[w] = bm[(((size_t)b * CC + c) * NW + w) * WW + j];
#pragma unroll
        for (int d = 0; d < 2; ++d) {
            // d=0: fg set = (t != c) = complement; d=1: bg set = (t == c)
            int last = -1, next = -1;
#pragma unroll
            for (int w = 0; w < NW; ++w) {
                u64 raw = (d == 0) ? ~wb[w] : wb[w];
                u64 mlo = (w < wi) ? raw : ((w == wi) ? (raw & lowmask) : 0ull);
                if (mlo) last = (w << 6) + 63 - __builtin_clzll(mlo | 1ull);
            }
#pragma unroll
            for (int w = NW - 1; w >= 0; --w) {
                u64 raw = (d == 0) ? ~wb[w] : wb[w];
                u64 mhi = (w > wi) ? raw : ((w == wi) ? (raw & himask) : 0ull);
                if (mhi) next = (w << 6) + (int)__builtin_ctzll(mhi | 0x8000000000000000ull);
            }
            float fwd = (last >= 0) ? (float)(i - last) : (INF_F + (float)(i + 1));
            float bwd = (next >= 0) ? (float)(next - i) : (INF_F + (float)(HH - i));
            float g = fminf(fwd, bwd);
            g2s[c * 2 + d][j] = g * g;
        }
    }
    __syncthreads();

    float dloc[6];
#pragma unroll
    for (int p6 = 0; p6 < 6; ++p6) {
        const float* g2 = g2s[p6];
        float mn = g2[j];
        for (int r = 1; r < WW; ++r) {
            float rr = (float)(r * r);          // exact fp32 integer
            if (rr >= mn) break;                // all further candidates >= rr >= mn
            int kl = j - r, kr = j + r;
            if (kl >= 0) mn = fminf(mn, rr + g2[kl]);
            if (kr < WW) mn = fminf(mn, rr + g2[kr]);
        }
        dloc[p6] = sqrtf(mn);
    }

    size_t rowoff = (size_t)i * WW + j;
    int lane = j & 63, wid = j >> 6;
#pragma unroll
    for (int p6 = 0; p6 < 6; ++p6) {
        planes[((size_t)(b * 6 + p6)) * PLANE + rowoff] = dloc[p6];
        float v = dloc[p6];
        for (int off = 32; off > 0; off >>= 1) v = fmaxf(v, __shfl_down(v, off));
        if (lane == 0) wmax[p6][wid] = v;
    }
    __syncthreads();
    if (j < 6) {
        float mx = wmax[j][0];
#pragma unroll
        for (int w = 1; w < WW / 64; ++w) mx = fmaxf(mx, wmax[j][w]);
        rowmax[(size_t)(b * 6 + j) * HH + i] = mx;   // plain store, no atomic
    }
}

// One block per plane p: max over HH row-maxima -> maxv[p].
__global__ __launch_bounds__(HH) void maxreduce(const float* __restrict__ rowmax,
                                                float* __restrict__ maxv) {
    __shared__ float wmax[HH / 64];
    int p = blockIdx.x;
    int t = threadIdx.x;
    float v = rowmax[(size_t)p * HH + t];
    for (int off = 32; off > 0; off >>= 1) v = fmaxf(v, __shfl_down(v, off));
    int lane = t & 63, wid = t >> 6;
    if (lane == 0) wmax[wid] = v;
    __syncthreads();
    if (t == 0) {
        float mx = wmax[0];
#pragma unroll
        for (int w = 1; w < HH / 64; ++w) mx = fmaxf(mx, wmax[w]);
        maxv[p] = mx;
    }
}

// Grid-stride: softmax over C, sdf = bg/max_bg - fg/max_fg (0 if mask empty),
// accumulate probs*sdf; block partial -> plain store (no atomics).
__global__ __launch_bounds__(RL_THREADS) void reduce_loss(const float* __restrict__ logits,
                                                          const float* __restrict__ planes,
                                                          const float* __restrict__ maxv,
                                                          const int* __restrict__ flags,
                                                          float* __restrict__ partials) {
    __shared__ float wsum[RL_THREADS / 64];
    const int total = BB * PLANE;
    const int stride = RL_BLOCKS * RL_THREADS;
    float local = 0.0f;
    for (int gid = blockIdx.x * RL_THREADS + threadIdx.x; gid < total; gid += stride) {
        int b = gid / PLANE;
        int pix = gid - b * PLANE;

        const float* lg = logits + (size_t)b * CC * PLANE + pix;
        float l0 = lg[0], l1 = lg[PLANE], l2 = lg[2 * PLANE];
        float mx = fmaxf(l0, fmaxf(l1, l2));
        float x0 = expf(l0 - mx), x1 = expf(l1 - mx), x2 = expf(l2 - mx);
        float s = x0 + x1 + x2;
        float pr0 = x0 / s, pr1 = x1 / s, pr2 = x2 / s;

        const float* pb = planes + (size_t)b * 6 * PLANE + pix;
        float pix_acc = 0.0f;
#pragma unroll
        for (int c = 0; c < CC; ++c) {
            int m = b * CC + c;
            float sdf = 0.0f;
            if (flags[m]) {
                float fg = pb[(size_t)(c * 2 + 0) * PLANE];
                float bg = pb[(size_t)(c * 2 + 1) * PLANE];
                float mfg = fmaxf(maxv[m * 2 + 0], 1e-12f);
                float mbg = fmaxf(maxv[m * 2 + 1], 1e-12f);
                sdf = bg / mbg - fg / mfg;
            }
            pix_acc += (c == 0 ? pr0 : (c == 1 ? pr1 : pr2)) * sdf;
        }
        local += pix_acc;
    }

    for (int off = 32; off > 0; off >>= 1) local += __shfl_down(local, off);
    int lane = threadIdx.x & 63, wid = threadIdx.x >> 6;
    if (lane == 0) wsum[wid] = local;
    __syncthreads();
    if (threadIdx.x == 0) {
        float bs = 0.0f;
#pragma unroll
        for (int w = 0; w < RL_THREADS / 64; ++w) bs += wsum[w];
        partials[blockIdx.x] = bs;
    }
}

__global__ __launch_bounds__(256) void final_sum(const float* __restrict__ partials,
                                                 float* __restrict__ out) {
    __shared__ float wsum[4];
    int t = threadIdx.x;
    float local = 0.0f;
    for (int i = t; i < RL_BLOCKS; i += 256) local += partials[i];
    for (int off = 32; off > 0; off >>= 1) local += __shfl_down(local, off);
    int lane = t & 63, wid = t >> 6;
    if (lane == 0) wsum[wid] = local;
    __syncthreads();
    if (t == 0) {
        float s = wsum[0] + wsum[1] + wsum[2] + wsum[3];
        out[0] = s / (float)((size_t)BB * CC * PLANE);
    }
}

extern "C" void kernel_launch(void* const* d_in, const int* in_sizes, int n_in,
                              void* d_out, int out_size, void* d_ws, size_t ws_size,
                              hipStream_t stream) {
    const float* logits = (const float*)d_in[0];   // [8,3,384,384] f32
    const int* targets = (const int*)d_in[1];      // [8,384,384] i32
    float* out = (float*)d_out;                    // scalar f32

    float* planes = (float*)d_ws;                               // 48 * PLANE floats
    u64* bm = (u64*)(planes + (size_t)NPLANES * PLANE);         // 8*3*6*384 u64
    float* rowmax = (float*)(bm + (size_t)BB * CC * NW * WW);   // 48*HH floats
    float* maxv = rowmax + (size_t)NPLANES * HH;                // 48 floats
    int* flags = (int*)(maxv + NPLANES);                        // 24 ints
    float* partials = (float*)(flags + NMASK);                  // RL_BLOCKS floats

    initk<<<1, 64, 0, stream>>>(flags);

    buildbm<<<BB * NW, WW, 0, stream>>>(targets, bm, flags);    // 48 blocks

    {
        dim3 grid(HH, BB);                                      // 384 x 8 = 3072 blocks
        edt_fused<<<grid, WW, 0, stream>>>(bm, planes, rowmax);
    }

    maxreduce<<<NPLANES, HH, 0, stream>>>(rowmax, maxv);        // 48 blocks

    reduce_loss<<<RL_BLOCKS, RL_THREADS, 0, stream>>>(logits, planes, maxv, flags, partials);

    final_sum<<<1, 256, 0, stream>>>(partials, out);
}

// Round 4
// 145.747 us; speedup vs baseline: 4.5714x; 1.0974x over previous
//
#include <hip/hip_runtime.h>

typedef unsigned long long u64;

#define HH 384
#define WW 384
#define BB 8
#define CC 3
#define NMASK (BB*CC)        // 24
#define PLANE (HH*WW)        // 147456
#define NPLANES (NMASK*2)    // 48
#define NW 6                 // 384 rows = 6 x 64-bit words exactly
#define INF_F 1.0e6f

// ---------------------------------------------------------------------------
// ws layout:
//   u64   bm[BB][CC][NW][WW]       column seed bitmask
//   float psum[NPLANES][HH]        per-(plane,row-block) sum of prob*dist
//   float rowmax[NPLANES][HH]      per-(plane,row-block) max dist
// Distances are never materialized: loss = sum_m S_bg/max_bg - S_fg/max_fg
// (divide-after-sum reorder; |delta| ~1e-7 rel, threshold 4.6e-4).
// Empty-mask test: mask non-empty <=> max_bg <= 1000 (real EDT max < 542,
// empty-set distances >= 1e6).
// ---------------------------------------------------------------------------

// One block per (b, w): 384 threads, thread j builds the 64-row bitmask word
// for its column for all 3 classes.
__global__ __launch_bounds__(WW) void buildbm(const int* __restrict__ targets,
                                              u64* __restrict__ bm) {
    int b = blockIdx.x / NW;
    int w = blockIdx.x - b * NW;
    int j = threadIdx.x;
    const int* tg = targets + (size_t)b * PLANE + (w * 64) * WW + j;
    u64 m0 = 0, m1 = 0, m2 = 0;
#pragma unroll 8
    for (int r = 0; r < 64; ++r) {
        int t = tg[r * WW];
        u64 bit = 1ull << r;
        if (t == 0) m0 |= bit;
        else if (t == 1) m1 |= bit;
        else m2 |= bit;
    }
    bm[(((size_t)b * CC + 0) * NW + w) * WW + j] = m0;
    bm[(((size_t)b * CC + 1) * NW + w) * WW + j] = m1;
    bm[(((size_t)b * CC + 2) * NW + w) * WW + j] = m2;
}

// One block per (b, row i): thread j reconstructs the exact column distance g
// for all 6 planes from the bitmasks (bit-identical to the reference scan:
// integer dist, or 1e6+k when no seed), squares into LDS, row-EDT via
// expanding-ring search (safe prune: r*r >= mn implies candidate >= mn),
// then immediately consumes the distances: softmax(logits) weights, per-plane
// weighted sum + max, block-reduced to 12 scalars. No distance planes stored.
__global__ __launch_bounds__(WW) void edt_fused(const u64* __restrict__ bm,
                                                const float* __restrict__ logits,
                                                float* __restrict__ psum,
                                                float* __restrict__ rowmax) {
    __shared__ float g2s[6][WW];
    __shared__ float wsum[6][WW / 64];
    __shared__ float wmax[6][WW / 64];
    int i = blockIdx.x;
    int b = blockIdx.y;
    int j = threadIdx.x;

    // issue logits loads early (independent of everything below)
    const float* lg = logits + ((size_t)b * CC * HH + i) * WW + j;
    float l0 = lg[0], l1 = lg[(size_t)HH * WW], l2 = lg[2 * (size_t)HH * WW];

    int wi = i >> 6, bi = i & 63;
    u64 lowmask = (bi == 63) ? ~0ull : ((1ull << (bi + 1)) - 1ull); // bits 0..bi
    u64 himask = ~(lowmask >> 1);                                   // bits bi..63

#pragma unroll
    for (int c = 0; c < CC; ++c) {
        u64 wb[NW];
#pragma unroll
        for (int w = 0; w < NW; ++w)
            wb[w] = bm[(((size_t)b * CC + c) * NW + w) * WW + j];
#pragma unroll
        for (int d = 0; d < 2; ++d) {
            // d=0: fg set = (t != c) = complement; d=1: bg set = (t == c)
            int last = -1, next = -1;
#pragma unroll
            for (int w = 0; w < NW; ++w) {
                u64 raw = (d == 0) ? ~wb[w] : wb[w];
                u64 mlo = (w < wi) ? raw : ((w == wi) ? (raw & lowmask) : 0ull);
                if (mlo) last = (w << 6) + 63 - __builtin_clzll(mlo | 1ull);
            }
#pragma unroll
            for (int w = NW - 1; w >= 0; --w) {
                u64 raw = (d == 0) ? ~wb[w] : wb[w];
                u64 mhi = (w > wi) ? raw : ((w == wi) ? (raw & himask) : 0ull);
                if (mhi) next = (w << 6) + (int)__builtin_ctzll(mhi | 0x8000000000000000ull);
            }
            float fwd = (last >= 0) ? (float)(i - last) : (INF_F + (float)(i + 1));
            float bwd = (next >= 0) ? (float)(next - i) : (INF_F + (float)(HH - i));
            float g = fminf(fwd, bwd);
            g2s[c * 2 + d][j] = g * g;
        }
    }
    __syncthreads();

    // softmax over the 3 classes at this pixel
    float mx = fmaxf(l0, fmaxf(l1, l2));
    float x0 = expf(l0 - mx), x1 = expf(l1 - mx), x2 = expf(l2 - mx);
    float rs = 1.0f / (x0 + x1 + x2);
    float pr[3] = {x0 * rs, x1 * rs, x2 * rs};

    float dloc[6];
#pragma unroll
    for (int p6 = 0; p6 < 6; ++p6) {
        const float* g2 = g2s[p6];
        float mn = g2[j];
        for (int r = 1; r < WW; ++r) {
            float rr = (float)(r * r);          // exact fp32 integer
            if (rr >= mn) break;                // all further candidates >= rr >= mn
            int kl = j - r, kr = j + r;
            if (kl >= 0) mn = fminf(mn, rr + g2[kl]);
            if (kr < WW) mn = fminf(mn, rr + g2[kr]);
        }
        dloc[p6] = sqrtf(mn);
    }

    // per-plane weighted sum (prob of class c = p6>>1) and max, block-reduced
    int lane = j & 63, wid = j >> 6;
#pragma unroll
    for (int p6 = 0; p6 < 6; ++p6) {
        float sv = pr[p6 >> 1] * dloc[p6];
        float mv = dloc[p6];
        for (int off = 32; off > 0; off >>= 1) {
            sv += __shfl_down(sv, off);
            mv = fmaxf(mv, __shfl_down(mv, off));
        }
        if (lane == 0) { wsum[p6][wid] = sv; wmax[p6][wid] = mv; }
    }
    __syncthreads();
    if (j < 6) {
        float s = wsum[j][0], m = wmax[j][0];
#pragma unroll
        for (int w = 1; w < WW / 64; ++w) {
            s += wsum[j][w];
            m = fmaxf(m, wmax[j][w]);
        }
        psum[(size_t)(b * 6 + j) * HH + i] = s;
        rowmax[(size_t)(b * 6 + j) * HH + i] = m;
    }
}

// Single block: reduce psum/rowmax over rows per plane, combine planes.
__global__ __launch_bounds__(WW) void final_k(const float* __restrict__ psum,
                                              const float* __restrict__ rowmax,
                                              float* __restrict__ out) {
    __shared__ float sS[NPLANES], sM[NPLANES];
    int t = threadIdx.x;
    int p = t >> 3;      // 0..47: plane
    int l = t & 7;       // 8 threads per plane
    float s = 0.0f, m = 0.0f;
    for (int i = l; i < HH; i += 8) {
        s += psum[(size_t)p * HH + i];
        m = fmaxf(m, rowmax[(size_t)p * HH + i]);
    }
#pragma unroll
    for (int off = 4; off > 0; off >>= 1) {
        s += __shfl_down(s, off, 8);
        m = fmaxf(m, __shfl_down(m, off, 8));
    }
    if (l == 0) { sS[p] = s; sM[p] = m; }
    __syncthreads();
    if (t == 0) {
        float tot = 0.0f;
        for (int mk = 0; mk < NMASK; ++mk) {
            float Sf = sS[2 * mk],     Mf = sM[2 * mk];
            float Sb = sS[2 * mk + 1], Mb = sM[2 * mk + 1];
            if (Mb <= 1000.0f) {   // mask non-empty
                tot += Sb / fmaxf(Mb, 1e-12f) - Sf / fmaxf(Mf, 1e-12f);
            }
        }
        out[0] = tot / (float)((size_t)BB * CC * PLANE);
    }
}

extern "C" void kernel_launch(void* const* d_in, const int* in_sizes, int n_in,
                              void* d_out, int out_size, void* d_ws, size_t ws_size,
                              hipStream_t stream) {
    const float* logits = (const float*)d_in[0];   // [8,3,384,384] f32
    const int* targets = (const int*)d_in[1];      // [8,384,384] i32
    float* out = (float*)d_out;                    // scalar f32

    u64* bm = (u64*)d_ws;                                   // 8*3*6*384 u64
    float* psum = (float*)(bm + (size_t)BB * CC * NW * WW); // 48*HH floats
    float* rowmax = psum + (size_t)NPLANES * HH;            // 48*HH floats

    buildbm<<<BB * NW, WW, 0, stream>>>(targets, bm);       // 48 blocks

    {
        dim3 grid(HH, BB);                                  // 384 x 8 = 3072 blocks
        edt_fused<<<grid, WW, 0, stream>>>(bm, logits, psum, rowmax);
    }

    final_k<<<1, WW, 0, stream>>>(psum, rowmax, out);
}

// Round 5
// 102.692 us; speedup vs baseline: 6.4880x; 1.4193x over previous
//
#include <hip/hip_runtime.h>

typedef unsigned long long u64;
typedef unsigned short u16;

#define HH 384
#define WW 384
#define BB 8
#define CC 3
#define NMASK (BB*CC)        // 24
#define PLANE (HH*WW)        // 147456
#define NW 6                 // 384 rows = 6 x 64-bit words
#define GROUPS 24            // row groups of 16
#define ROWS_PG 16
#define INF_F 1.0e6f

// ---------------------------------------------------------------------------
// ws layout:
//   u64    bm[BB][CC][NW][WW]          column seed bitmasks (442368 B)
//   float4 out4[BB][CC][GROUPS]        per-(b,c,rowgroup): {sum_fg, sum_bg, max_fg, max_bg}
// loss = sum_m S_bg/max_bg - S_fg/max_fg  (divide-after-sum; ~1e-7 rel vs 4.6e-4 thr)
// mask non-empty <=> max_bg <= 1000 (real EDT max < 542; empty-set dists >= 1e6)
// ---------------------------------------------------------------------------

// Grid (BB, NW, 4): thread j builds a 16-bit partial of the 64-row bitmask word
// for its column, all 3 classes. u16 stores into the right bytes of the u64
// array (little-endian) -> no atomics, no zero-init needed.
__global__ __launch_bounds__(WW) void buildbm(const int* __restrict__ targets,
                                              u16* __restrict__ bm16) {
    int b = blockIdx.x, w = blockIdx.y, q = blockIdx.z;
    int j = threadIdx.x;
    const int* tg = targets + (size_t)b * PLANE + (w * 64 + q * 16) * WW + j;
    unsigned m0 = 0, m1 = 0, m2 = 0;
#pragma unroll
    for (int r = 0; r < 16; ++r) {
        int t = tg[r * WW];
        unsigned bit = 1u << r;
        m0 |= (t == 0) ? bit : 0u;
        m1 |= (t == 1) ? bit : 0u;
        m2 |= (t == 2) ? bit : 0u;
    }
    size_t base = (((size_t)b * CC) * NW + w) * WW + j;          // c = 0
    bm16[base * 4 + q] = (u16)m0;
    bm16[(base + (size_t)NW * WW) * 4 + q] = (u16)m1;
    bm16[(base + 2 * (size_t)NW * WW) * 4 + q] = (u16)m2;
}

// Grid (GROUPS, BB, CC): block handles 16 rows x 384 cols for one class's
// fg (~mask) and bg (mask) planes. Thread j loads its column's 6 bitmask
// words ONCE, precomputes cross-word prev/next seed anchors, then per row the
// exact reference column-distance g is ~30 branchless ops. Row g^2 tiles go
// through double-buffered LDS (one barrier per row); the ring search
// (safe prune: r*r >= mn => candidate >= mn) consumes them; softmax-weighted
// sums and maxima accumulate in registers, block-reduced once at the end.
__global__ __launch_bounds__(WW) void edt16(const u64* __restrict__ bm,
                                            const float* __restrict__ logits,
                                            float4* __restrict__ out4) {
    __shared__ float g2s[2][2][WW];
    __shared__ float red[4][WW / 64];
    int g = blockIdx.x, b = blockIdx.y, c = blockIdx.z;
    int j = threadIdx.x;
    int w = g >> 2;                       // word containing rows 16g..16g+15

    u64 wb[NW];
#pragma unroll
    for (int wq = 0; wq < NW; ++wq)
        wb[wq] = bm[(((size_t)b * CC + c) * NW + wq) * WW + j];

    // anchors: P* = highest seed index in words < w, N* = lowest in words > w
    int Pbg = -1, Pfg = -1, Nbg = -1, Nfg = -1;
#pragma unroll
    for (int wq = 0; wq < NW; ++wq) {
        u64 bw = wb[wq], fw = ~wb[wq];
        if (wq < w) {
            if (bw) Pbg = wq * 64 + 63 - __builtin_clzll(bw | 1ull);
            if (fw) Pfg = wq * 64 + 63 - __builtin_clzll(fw | 1ull);
        }
    }
#pragma unroll
    for (int wq = NW - 1; wq >= 0; --wq) {
        u64 bw = wb[wq], fw = ~wb[wq];
        if (wq > w) {
            if (bw) Nbg = wq * 64 + (int)__builtin_ctzll(bw | 0x8000000000000000ull);
            if (fw) Nfg = wq * 64 + (int)__builtin_ctzll(fw | 0x8000000000000000ull);
        }
    }
    u64 bgw = wb[w], fgw = ~wb[w];
    const float* lgbase = logits + (size_t)b * CC * PLANE + j;

    float sfg = 0.f, sbg = 0.f, mfg = 0.f, mbg = 0.f;
    int i0 = g * ROWS_PG;
    for (int rl = 0; rl < ROWS_PG; ++rl) {
        int i = i0 + rl;
        int bi = i & 63;
        u64 lowmask = ((1ull << bi) << 1) - 1ull;   // bits 0..bi (bi=63 -> ~0)
        u64 himask = ~(lowmask >> 1);               // bits bi..63

        // bg: set = (t == c)
        u64 lo = bgw & lowmask;
        int last = lo ? (w * 64 + 63 - __builtin_clzll(lo | 1ull)) : Pbg;
        u64 hi = bgw & himask;
        int next = hi ? (w * 64 + (int)__builtin_ctzll(hi | 0x8000000000000000ull)) : Nbg;
        float fwd = (last >= 0) ? (float)(i - last) : (INF_F + (float)(i + 1));
        float bwd = (next >= 0) ? (float)(next - i) : (INF_F + (float)(HH - i));
        float gb = fminf(fwd, bwd);
        // fg: set = (t != c)
        lo = fgw & lowmask;
        last = lo ? (w * 64 + 63 - __builtin_clzll(lo | 1ull)) : Pfg;
        hi = fgw & himask;
        next = hi ? (w * 64 + (int)__builtin_ctzll(hi | 0x8000000000000000ull)) : Nfg;
        fwd = (last >= 0) ? (float)(i - last) : (INF_F + (float)(i + 1));
        bwd = (next >= 0) ? (float)(next - i) : (INF_F + (float)(HH - i));
        float gf = fminf(fwd, bwd);

        int par = rl & 1;
        g2s[par][0][j] = gf * gf;
        g2s[par][1][j] = gb * gb;
        // issue logits loads pre-barrier; used post-barrier
        float l0 = lgbase[(size_t)(0 * HH + i) * WW];
        float l1 = lgbase[(size_t)(1 * HH + i) * WW];
        float l2 = lgbase[(size_t)(2 * HH + i) * WW];
        __syncthreads();

        float mx = fmaxf(l0, fmaxf(l1, l2));
        float x0 = expf(l0 - mx), x1 = expf(l1 - mx), x2 = expf(l2 - mx);
        float pr = ((c == 0) ? x0 : (c == 1) ? x1 : x2) / (x0 + x1 + x2);

        const float* g2 = g2s[par][0];
        float mn = g2[j];
        for (int r = 1; r < WW; ++r) {
            float rr = (float)(r * r);             // exact fp32 integer
            if (rr >= mn) break;                   // further candidates >= rr >= mn
            int kl = j - r, kr = j + r;
            if (kl >= 0) mn = fminf(mn, rr + g2[kl]);
            if (kr < WW) mn = fminf(mn, rr + g2[kr]);
        }
        float df = sqrtf(mn);

        g2 = g2s[par][1];
        mn = g2[j];
        for (int r = 1; r < WW; ++r) {
            float rr = (float)(r * r);
            if (rr >= mn) break;
            int kl = j - r, kr = j + r;
            if (kl >= 0) mn = fminf(mn, rr + g2[kl]);
            if (kr < WW) mn = fminf(mn, rr + g2[kr]);
        }
        float db = sqrtf(mn);

        sfg += pr * df;
        sbg += pr * db;
        mfg = fmaxf(mfg, df);
        mbg = fmaxf(mbg, db);
        // no trailing barrier needed: next iteration writes the OTHER parity,
        // and the next barrier collectively guarantees 2-iterations-back done.
    }

    int lane = j & 63, wid = j >> 6;
    for (int off = 32; off > 0; off >>= 1) {
        sfg += __shfl_down(sfg, off);
        sbg += __shfl_down(sbg, off);
        mfg = fmaxf(mfg, __shfl_down(mfg, off));
        mbg = fmaxf(mbg, __shfl_down(mbg, off));
    }
    if (lane == 0) { red[0][wid] = sfg; red[1][wid] = sbg; red[2][wid] = mfg; red[3][wid] = mbg; }
    __syncthreads();
    if (j == 0) {
        float a = red[0][0], s = red[1][0], mf = red[2][0], mb = red[3][0];
#pragma unroll
        for (int t = 1; t < WW / 64; ++t) {
            a += red[0][t]; s += red[1][t];
            mf = fmaxf(mf, red[2][t]); mb = fmaxf(mb, red[3][t]);
        }
        out4[((size_t)b * CC + c) * GROUPS + g] = make_float4(a, s, mf, mb);
    }
}

// Single block: reduce the 576 float4 partials -> scalar loss.
__global__ __launch_bounds__(NMASK* GROUPS) void final_k(const float4* __restrict__ out4,
                                                         float* __restrict__ out) {
    __shared__ float4 v[NMASK * GROUPS];
    __shared__ float contrib[NMASK];
    int t = threadIdx.x;
    v[t] = out4[t];
    __syncthreads();
    if (t < NMASK) {
        float sfg = 0.f, sbg = 0.f, mfg = 0.f, mbg = 0.f;
        for (int g = 0; g < GROUPS; ++g) {
            float4 x = v[t * GROUPS + g];
            sfg += x.x; sbg += x.y;
            mfg = fmaxf(mfg, x.z); mbg = fmaxf(mbg, x.w);
        }
        float cv = 0.f;
        if (mbg <= 1000.0f)   // mask non-empty
            cv = sbg / fmaxf(mbg, 1e-12f) - sfg / fmaxf(mfg, 1e-12f);
        contrib[t] = cv;
    }
    __syncthreads();
    if (t == 0) {
        float tot = 0.f;
        for (int mk = 0; mk < NMASK; ++mk) tot += contrib[mk];
        out[0] = tot / (float)((size_t)BB * CC * PLANE);
    }
}

extern "C" void kernel_launch(void* const* d_in, const int* in_sizes, int n_in,
                              void* d_out, int out_size, void* d_ws, size_t ws_size,
                              hipStream_t stream) {
    const float* logits = (const float*)d_in[0];   // [8,3,384,384] f32
    const int* targets = (const int*)d_in[1];      // [8,384,384] i32
    float* out = (float*)d_out;                    // scalar f32

    u64* bm = (u64*)d_ws;                                        // 55296 u64
    float4* out4 = (float4*)(bm + (size_t)BB * CC * NW * WW);    // 576 float4 (16B-aligned)

    {
        dim3 grid(BB, NW, 4);                                    // 192 blocks
        buildbm<<<grid, WW, 0, stream>>>(targets, (u16*)bm);
    }
    {
        dim3 grid(GROUPS, BB, CC);                               // 24*8*3 = 576 blocks
        edt16<<<grid, WW, 0, stream>>>(bm, logits, out4);
    }
    final_k<<<1, NMASK * GROUPS, 0, stream>>>(out4, out);
}